// Round 1
// baseline (291.796 us; speedup 1.0000x reference)
//
#include <hip/hip_runtime.h>
#include <math.h>

#define TB 256
#define NPIX (8 * 224 * 224)   // 401408
#define HW   (224 * 224)       // 50176

// ---------------------------------------------------------------------------
// Pack kernel: one block of 64 threads.
//  - Re-layout weights from d = c*9 + s (patch channel-major order) into
//    tap-major wp[(s*64 + c)*16 + o], o = concat(w1,w2,w3[4],w4[5],w5[5]).
//  - Compute ww[j] = sum_d w3[d][j]^2 with a deterministic shuffle reduce.
// ---------------------------------------------------------------------------
__global__ void kpack(const float* __restrict__ w1, const float* __restrict__ w2,
                      const float* __restrict__ w3, const float* __restrict__ w4,
                      const float* __restrict__ w5, float* __restrict__ wp,
                      float* __restrict__ wwv)
{
  const int lane = threadIdx.x;  // 0..63
  float pw0 = 0.f, pw1 = 0.f, pw2 = 0.f, pw3 = 0.f;
  for (int it = 0; it < 9; ++it) {
    const int d = lane + it * 64;        // 0..575
    const int c = d / 9;
    const int s = d - c * 9;
    float* dst = wp + (size_t)(s * 64 + c) * 16;
    dst[0] = w1[d];
    dst[1] = w2[d];
    const float v0 = w3[d * 4 + 0], v1 = w3[d * 4 + 1];
    const float v2 = w3[d * 4 + 2], v3 = w3[d * 4 + 3];
    dst[2] = v0; dst[3] = v1; dst[4] = v2; dst[5] = v3;
    pw0 = fmaf(v0, v0, pw0); pw1 = fmaf(v1, v1, pw1);
    pw2 = fmaf(v2, v2, pw2); pw3 = fmaf(v3, v3, pw3);
#pragma unroll
    for (int j = 0; j < 5; ++j) dst[6 + j]  = w4[d * 5 + j];
#pragma unroll
    for (int j = 0; j < 5; ++j) dst[11 + j] = w5[d * 5 + j];
  }
#pragma unroll
  for (int off = 32; off > 0; off >>= 1) {
    pw0 += __shfl_down(pw0, off);
    pw1 += __shfl_down(pw1, off);
    pw2 += __shfl_down(pw2, off);
    pw3 += __shfl_down(pw3, off);
  }
  if (lane == 0) { wwv[0] = pw0; wwv[1] = pw1; wwv[2] = pw2; wwv[3] = pw3; }
}

// ---------------------------------------------------------------------------
// Main kernel: 1 pixel per thread. acc[16] + xx in VGPRs.
// Weights are wave-uniform (loop-index addressed) -> scalar loads.
// ---------------------------------------------------------------------------
__global__ __launch_bounds__(TB) void kmain(
    const float* __restrict__ x, const float* __restrict__ wp,
    const float* __restrict__ wwv, const float* __restrict__ gpt,
    const float* __restrict__ c4p, const float* __restrict__ c5p,
    float* __restrict__ out)
{
  const int p = blockIdx.x * TB + threadIdx.x;   // grid covers exactly NPIX
  const int b = p / HW;
  const int rem = p - b * HW;
  const int y = rem / 224;
  const int xc = rem - y * 224;
  const float* __restrict__ xb = x + (size_t)b * HW * 64;

  float acc[16];
#pragma unroll
  for (int o = 0; o < 16; ++o) acc[o] = 0.f;
  float xx = 0.f;

#pragma unroll
  for (int ky = 0; ky < 3; ++ky) {
    const int yy = y + ky - 1;
    if ((unsigned)yy >= 224u) continue;   // zero padding: contributes nothing
#pragma unroll
    for (int kx = 0; kx < 3; ++kx) {
      const int xxc = xc + kx - 1;
      if ((unsigned)xxc >= 224u) continue;
      const float* __restrict__ xp = xb + ((size_t)yy * 224 + xxc) * 64;
      const float* __restrict__ wr = wp + (size_t)(ky * 3 + kx) * 64 * 16;
#pragma unroll 2
      for (int c4 = 0; c4 < 16; ++c4) {
        const float4 xv = *(const float4*)(xp + c4 * 4);
        const float* __restrict__ w = wr + (size_t)c4 * 64;
#pragma unroll
        for (int j = 0; j < 4; ++j) {
          const float xj = (j == 0) ? xv.x : (j == 1) ? xv.y : (j == 2) ? xv.z : xv.w;
          xx = fmaf(xj, xj, xx);
#pragma unroll
          for (int o = 0; o < 16; ++o)
            acc[o] = fmaf(xj, w[j * 16 + o], acc[o]);
        }
      }
    }
  }

  const float g   = gpt[0];
  const float cc4 = c4p[0];
  const float cc5 = c5p[0];
  const float w0 = wwv[0], w1 = wwv[1], w2 = wwv[2], w3 = wwv[3];

  float r[16];
  r[0] = acc[0];
  r[1] = tanhf(acc[1]);
  r[2] = expf(-g * (xx - 2.f * acc[2] + w0));
  r[3] = expf(-g * (xx - 2.f * acc[3] + w1));
  r[4] = expf(-g * (xx - 2.f * acc[4] + w2));
  r[5] = expf(-g * (xx - 2.f * acc[5] + w3));
#pragma unroll
  for (int j = 0; j < 5; ++j) {
    const float t = acc[6 + j] + cc4;
    r[6 + j] = t * t * t;
  }
#pragma unroll
  for (int j = 0; j < 5; ++j) {
    const float t = acc[11 + j] + cc5;
    const float t2 = t * t;
    r[11 + j] = t2 * t2 * t;
  }

  float4* __restrict__ op = (float4*)(out + (size_t)p * 16);
  op[0] = make_float4(r[0],  r[1],  r[2],  r[3]);
  op[1] = make_float4(r[4],  r[5],  r[6],  r[7]);
  op[2] = make_float4(r[8],  r[9],  r[10], r[11]);
  op[3] = make_float4(r[12], r[13], r[14], r[15]);
}

extern "C" void kernel_launch(void* const* d_in, const int* in_sizes, int n_in,
                              void* d_out, int out_size, void* d_ws, size_t ws_size,
                              hipStream_t stream) {
  const float* x  = (const float*)d_in[0];
  const float* w1 = (const float*)d_in[1];
  const float* w2 = (const float*)d_in[2];
  const float* w3 = (const float*)d_in[3];
  const float* w4 = (const float*)d_in[4];
  const float* w5 = (const float*)d_in[5];
  const float* g  = (const float*)d_in[6];
  const float* c4 = (const float*)d_in[7];
  const float* c5 = (const float*)d_in[8];
  float* out = (float*)d_out;

  float* wp  = (float*)d_ws;     // 9*64*16 = 9216 floats (36 KiB)
  float* wwv = wp + 9216;        // 4 floats

  kpack<<<1, 64, 0, stream>>>(w1, w2, w3, w4, w5, wp, wwv);
  kmain<<<NPIX / TB, TB, 0, stream>>>(x, wp, wwv, g, c4, c5, out);
}

// Round 2
// 151.703 us; speedup vs baseline: 1.9235x; 1.9235x over previous
//
#include <hip/hip_runtime.h>
#include <math.h>

#define NPIX (8 * 224 * 224)   // 401408
#define HW   (224 * 224)       // 50176

// Tile geometry: 32 wide x 8 tall per block (256 threads, 1 px/thread).
#define TX 32
#define TY 8
#define HX (TX + 2)            // 34 halo cols
#define HY (TY + 2)            // 10 halo rows
#define PSTRIDE 68             // ushorts per pixel (64 ch + pad), 136 B: 8B-aligned, bank-uniform
#define NSTAGE (HX * HY * 16)  // float4 units to stage: 340 px * 16 = 5440

// ---------------------------------------------------------------------------
// Pack kernel (unchanged from R1): tap-major weights wp[(s*64+c)*16+o],
// plus ww[j] = sum_d w3[d][j]^2.
// ---------------------------------------------------------------------------
__global__ void kpack(const float* __restrict__ w1, const float* __restrict__ w2,
                      const float* __restrict__ w3, const float* __restrict__ w4,
                      const float* __restrict__ w5, float* __restrict__ wp,
                      float* __restrict__ wwv)
{
  const int lane = threadIdx.x;  // 0..63
  float pw0 = 0.f, pw1 = 0.f, pw2 = 0.f, pw3 = 0.f;
  for (int it = 0; it < 9; ++it) {
    const int d = lane + it * 64;        // 0..575
    const int c = d / 9;
    const int s = d - c * 9;
    float* dst = wp + (size_t)(s * 64 + c) * 16;
    dst[0] = w1[d];
    dst[1] = w2[d];
    const float v0 = w3[d * 4 + 0], v1 = w3[d * 4 + 1];
    const float v2 = w3[d * 4 + 2], v3 = w3[d * 4 + 3];
    dst[2] = v0; dst[3] = v1; dst[4] = v2; dst[5] = v3;
    pw0 = fmaf(v0, v0, pw0); pw1 = fmaf(v1, v1, pw1);
    pw2 = fmaf(v2, v2, pw2); pw3 = fmaf(v3, v3, pw3);
#pragma unroll
    for (int j = 0; j < 5; ++j) dst[6 + j]  = w4[d * 5 + j];
#pragma unroll
    for (int j = 0; j < 5; ++j) dst[11 + j] = w5[d * 5 + j];
  }
#pragma unroll
  for (int off = 32; off > 0; off >>= 1) {
    pw0 += __shfl_down(pw0, off);
    pw1 += __shfl_down(pw1, off);
    pw2 += __shfl_down(pw2, off);
    pw3 += __shfl_down(pw3, off);
  }
  if (lane == 0) { wwv[0] = pw0; wwv[1] = pw1; wwv[2] = pw2; wwv[3] = pw3; }
}

__device__ __forceinline__ unsigned bf16rne(float f) {
  unsigned u = __float_as_uint(f);
  u += 0x7fffu + ((u >> 16) & 1u);
  return u >> 16;
}

// ---------------------------------------------------------------------------
// Main kernel: LDS-staged x tile (bf16), thread-per-pixel compute with
// wave-uniform (scalar) weight loads.
// ---------------------------------------------------------------------------
__global__ __launch_bounds__(256) void kmain(
    const float* __restrict__ x, const float* __restrict__ wp,
    const float* __restrict__ wwv, const float* __restrict__ gpt,
    const float* __restrict__ c4p, const float* __restrict__ c5p,
    float* __restrict__ out)
{
  __shared__ unsigned short lds[HX * HY * PSTRIDE];  // 46240 B

  const int tid = threadIdx.x;
  const int bid = blockIdx.x;            // 0..1567
  const int b   = bid / 196;             // image
  const int t   = bid - b * 196;
  const int tyi = t / 7;
  const int txi = t - tyi * 7;
  const int y0  = tyi * TY;
  const int x0  = txi * TX;

  const float* __restrict__ xb = x + (size_t)b * HW * 64;

  // ---- Stage halo tile (fp32 global, coalesced) -> bf16 LDS ----
  for (int idx = tid; idx < NSTAGE; idx += 256) {
    const int f4 = idx & 15;             // which float4 of the 64 channels
    const int px = idx >> 4;             // 0..339
    const int ry = px / HX;
    const int rx = px - ry * HX;
    const int gy = y0 + ry - 1;
    const int gx = x0 + rx - 1;
    float4 v = make_float4(0.f, 0.f, 0.f, 0.f);
    if ((unsigned)gy < 224u && (unsigned)gx < 224u)
      v = *(const float4*)(xb + ((size_t)gy * 224 + gx) * 64 + f4 * 4);
    const unsigned h0 = bf16rne(v.x), h1 = bf16rne(v.y);
    const unsigned h2 = bf16rne(v.z), h3 = bf16rne(v.w);
    uint2 pack = make_uint2(h0 | (h1 << 16), h2 | (h3 << 16));
    *(uint2*)(&lds[px * PSTRIDE + f4 * 4]) = pack;
  }
  __syncthreads();

  // ---- Compute: 1 pixel per thread ----
  const int tx = tid & (TX - 1);
  const int ty = tid >> 5;

  float acc[16];
#pragma unroll
  for (int o = 0; o < 16; ++o) acc[o] = 0.f;
  float xx = 0.f;

#pragma unroll
  for (int ky = 0; ky < 3; ++ky) {
#pragma unroll
    for (int kx = 0; kx < 3; ++kx) {
      const int xrow = ((ty + ky) * HX + (tx + kx)) * PSTRIDE;
      const float* __restrict__ wr = wp + (size_t)(ky * 3 + kx) * 1024;
#pragma unroll 2
      for (int c4 = 0; c4 < 16; ++c4) {
        const uint2 v = *(const uint2*)(&lds[xrow + c4 * 4]);
        const float x0f = __uint_as_float(v.x << 16);
        const float x1f = __uint_as_float(v.x & 0xffff0000u);
        const float x2f = __uint_as_float(v.y << 16);
        const float x3f = __uint_as_float(v.y & 0xffff0000u);
        xx = fmaf(x0f, x0f, xx);
        xx = fmaf(x1f, x1f, xx);
        xx = fmaf(x2f, x2f, xx);
        xx = fmaf(x3f, x3f, xx);
        const float* __restrict__ w0 = wr + (c4 * 4 + 0) * 16;
        const float* __restrict__ w1 = wr + (c4 * 4 + 1) * 16;
        const float* __restrict__ w2 = wr + (c4 * 4 + 2) * 16;
        const float* __restrict__ w3 = wr + (c4 * 4 + 3) * 16;
#pragma unroll
        for (int o = 0; o < 16; ++o) acc[o] = fmaf(x0f, w0[o], acc[o]);
#pragma unroll
        for (int o = 0; o < 16; ++o) acc[o] = fmaf(x1f, w1[o], acc[o]);
#pragma unroll
        for (int o = 0; o < 16; ++o) acc[o] = fmaf(x2f, w2[o], acc[o]);
#pragma unroll
        for (int o = 0; o < 16; ++o) acc[o] = fmaf(x3f, w3[o], acc[o]);
      }
    }
  }

  // ---- Epilogue ----
  const float g   = gpt[0];
  const float cc4 = c4p[0];
  const float cc5 = c5p[0];
  const float q0 = wwv[0], q1 = wwv[1], q2 = wwv[2], q3 = wwv[3];

  float r[16];
  r[0] = acc[0];
  r[1] = tanhf(acc[1]);
  r[2] = expf(-g * (xx - 2.f * acc[2] + q0));
  r[3] = expf(-g * (xx - 2.f * acc[3] + q1));
  r[4] = expf(-g * (xx - 2.f * acc[4] + q2));
  r[5] = expf(-g * (xx - 2.f * acc[5] + q3));
#pragma unroll
  for (int j = 0; j < 5; ++j) {
    const float tt = acc[6 + j] + cc4;
    r[6 + j] = tt * tt * tt;
  }
#pragma unroll
  for (int j = 0; j < 5; ++j) {
    const float tt = acc[11 + j] + cc5;
    const float t2 = tt * tt;
    r[11 + j] = t2 * t2 * tt;
  }

  const int p = ((b * 224 + (y0 + ty)) * 224 + (x0 + tx));
  float4* __restrict__ op = (float4*)(out + (size_t)p * 16);
  op[0] = make_float4(r[0],  r[1],  r[2],  r[3]);
  op[1] = make_float4(r[4],  r[5],  r[6],  r[7]);
  op[2] = make_float4(r[8],  r[9],  r[10], r[11]);
  op[3] = make_float4(r[12], r[13], r[14], r[15]);
}

extern "C" void kernel_launch(void* const* d_in, const int* in_sizes, int n_in,
                              void* d_out, int out_size, void* d_ws, size_t ws_size,
                              hipStream_t stream) {
  const float* x  = (const float*)d_in[0];
  const float* w1 = (const float*)d_in[1];
  const float* w2 = (const float*)d_in[2];
  const float* w3 = (const float*)d_in[3];
  const float* w4 = (const float*)d_in[4];
  const float* w5 = (const float*)d_in[5];
  const float* g  = (const float*)d_in[6];
  const float* c4 = (const float*)d_in[7];
  const float* c5 = (const float*)d_in[8];
  float* out = (float*)d_out;

  float* wp  = (float*)d_ws;     // 9*64*16 = 9216 floats (36 KiB)
  float* wwv = wp + 9216;        // 4 floats

  kpack<<<1, 64, 0, stream>>>(w1, w2, w3, w4, w5, wp, wwv);
  kmain<<<1568, 256, 0, stream>>>(x, wp, wwv, g, c4, c5, out);
}